// Round 3
// baseline (68.809 us; speedup 1.0000x reference)
//
#include <hip/hip_runtime.h>
#include <math.h>

#define NPTS 4096
#define BLK 256
#define PAIR_BLOCKS (NPTS / 2)   // 2048: block b handles row b (j>b) + folded row 4095-b (j<b)
#define EV_BLOCKS 256
#define CNT_OFF ((PAIR_BLOCKS + EV_BLOCKS) * 4)   // byte offset of counter in d_ws

// ---------------- fast erf: Abramowitz-Stegun 7.1.26, |err| <= 1.5e-7 ----------------
__device__ __forceinline__ float fast_erf(float x) {
    const float ax = fabsf(x);
    const float t  = __builtin_amdgcn_rcpf(fmaf(0.3275911f, ax, 1.0f));
    float p = fmaf(t, 1.061405429f, -1.453152027f);
    p = fmaf(t, p, 1.421413741f);
    p = fmaf(t, p, -0.284496736f);
    p = fmaf(t, p, 0.254829592f);
    p *= t;
    const float e = __expf(-ax * ax);
    const float r = fmaf(-p, e, 1.0f);
    return copysignf(r, x);
}

// ---------------- block-level float reduction (deterministic; result in thread 0) ----------------
__device__ __forceinline__ float block_reduce_f(float v) {
    #pragma unroll
    for (int off = 32; off > 0; off >>= 1)
        v += __shfl_down(v, off, 64);
    __shared__ float smem[BLK / 64];
    const int lane = threadIdx.x & 63;
    const int wid  = threadIdx.x >> 6;
    if (lane == 0) smem[wid] = v;
    __syncthreads();
    float t = 0.f;
    if (threadIdx.x == 0) {
        #pragma unroll
        for (int w = 0; w < BLK / 64; ++w) t += smem[w];
    }
    return t;
}

// ---------------- kernel 1: event intensity, LDS-staged tables ----------------
__global__ __launch_bounds__(BLK) void ev_kernel(
        const int* __restrict__ eu, const int* __restrict__ ev,
        const float* __restrict__ et,
        const float2* __restrict__ z0, const float2* __restrict__ v0,
        float* __restrict__ evp, int nE) {
    __shared__ float zx[NPTS], zy[NPTS], vx[NPTS], vy[NPTS];   // 64 KB
    for (int k = threadIdx.x; k < NPTS; k += BLK) {
        const float2 z = z0[k];
        const float2 v = v0[k];
        zx[k] = z.x; zy[k] = z.y; vx[k] = v.x; vy[k] = v.y;
    }
    __syncthreads();

    const int stride = EV_BLOCKS * BLK;           // 65536
    const int base   = blockIdx.x * BLK + threadIdx.x;
    float acc = 0.f;
    // 16 strided iters cover 1,048,576 >= nE; batch 8 loads up-front to hide HBM latency
    #pragma unroll
    for (int it0 = 0; it0 < 16; it0 += 8) {
        int   u[8], w[8];
        float t[8];
        bool  act[8];
        #pragma unroll
        for (int k = 0; k < 8; ++k) {
            const int idx = base + (it0 + k) * stride;
            act[k] = (idx < nE);
            const int safe = act[k] ? idx : 0;
            u[k] = eu[safe]; w[k] = ev[safe]; t[k] = et[safe];
        }
        #pragma unroll
        for (int k = 0; k < 8; ++k) {
            const float dx = (zx[u[k]] - zx[w[k]]) + (vx[u[k]] - vx[w[k]]) * t[k];
            const float dy = (zy[u[k]] - zy[w[k]]) + (vy[u[k]] - vy[w[k]]) * t[k];
            const float d2 = fmaf(dx, dx, dy * dy);
            acc += act[k] ? d2 : 0.f;
        }
    }
    const float r = block_reduce_f(acc);
    if (threadIdx.x == 0) evp[blockIdx.x] = r;
}

// ---------------- kernel 2: pair integral, uniform-i rows, branchless; last block finalizes ----------------
__global__ __launch_bounds__(BLK, 4) void pair_kernel(
        const float2* __restrict__ z0, const float2* __restrict__ v0,
        const float* __restrict__ beta_p, const float* __restrict__ t0_p,
        const float* __restrict__ tn_p,
        float* __restrict__ pp, const float* __restrict__ evp,
        unsigned* __restrict__ cnt, float* __restrict__ out, int nE) {
    const int   i1 = blockIdx.x;              // direct row
    const int   i2 = NPTS - 1 - i1;           // folded row
    const float b  = beta_p[0];
    const float t0 = t0_p[0];
    const float tn = tn_p[0];
    const float C  = -0.88622692545275801365f * __expf(b);   // -sqrt(pi)/2 * e^b

    const float2 z1 = z0[i1], z2 = z0[i2];
    const float2 v1 = v0[i1], v2 = v0[i2];

    float acc = 0.f;
    #pragma unroll 4
    for (int it = 0; it < NPTS / BLK; ++it) {
        const int  j     = it * BLK + threadIdx.x;
        const bool fold  = (j < i1);
        const bool valid = (j != i1);
        const int  jj    = fold ? (NPTS - 1 - j) : j;

        const float2 zj = z0[jj];
        const float2 vj = v0[jj];
        const float zix = fold ? z2.x : z1.x;
        const float ziy = fold ? z2.y : z1.y;
        const float vix = fold ? v2.x : v1.x;
        const float viy = fold ? v2.y : v1.y;

        const float a  = zix - zj.x;
        const float bb = ziy - zj.y;
        const float m  = vix - vj.x;
        const float n  = viy - vj.y;

        const float s2    = fmaf(m, m, n * n);
        const float inv_s = __builtin_amdgcn_rsqf(s2);
        const float cross = fmaf(bb, m, -a * n);
        const float am    = fmaf(a, m, bb * n);

        const float q = cross * inv_s;
        const float E = __expf(-q * q);

        const float e1 = fast_erf(fmaf(s2, t0, am) * inv_s);
        const float e2 = fast_erf(fmaf(s2, tn, am) * inv_s);

        const float contrib = (C * E) * (e1 - e2) * inv_s;
        acc += valid ? contrib : 0.f;
    }

    const float r = block_reduce_f(acc);
    __shared__ bool amLast;
    if (threadIdx.x == 0) {
        __hip_atomic_store(&pp[i1], r, __ATOMIC_RELEASE, __HIP_MEMORY_SCOPE_AGENT);
        const unsigned old = __hip_atomic_fetch_add(cnt, 1u, __ATOMIC_ACQ_REL,
                                                    __HIP_MEMORY_SCOPE_AGENT);
        amLast = (old == PAIR_BLOCKS - 1);
    }
    __syncthreads();

    if (amLast) {
        // deterministic final combine (order fixed regardless of which block runs it)
        __shared__ double sd[BLK];
        double s = 0.0;
        #pragma unroll
        for (int k = threadIdx.x; k < PAIR_BLOCKS; k += BLK)
            s += (double)__hip_atomic_load(&pp[k], __ATOMIC_RELAXED,
                                           __HIP_MEMORY_SCOPE_AGENT);
        s += (double)evp[threadIdx.x];        // EV_BLOCKS == BLK, one slot per thread
        sd[threadIdx.x] = s;
        __syncthreads();
        for (int st = BLK / 2; st > 0; st >>= 1) {
            if (threadIdx.x < st) sd[threadIdx.x] += sd[threadIdx.x + st];
            __syncthreads();
        }
        if (threadIdx.x == 0)
            out[0] = (float)((double)nE * (double)b - sd[0]);
    }
}

extern "C" void kernel_launch(void* const* d_in, const int* in_sizes, int n_in,
                              void* d_out, int out_size, void* d_ws, size_t ws_size,
                              hipStream_t stream) {
    const int*    eu   = (const int*)d_in[0];
    const int*    ev   = (const int*)d_in[1];
    const float*  et   = (const float*)d_in[2];
    const float*  t0   = (const float*)d_in[3];
    const float*  tn   = (const float*)d_in[4];
    const float*  beta = (const float*)d_in[5];
    const float2* z0   = (const float2*)d_in[6];
    const float2* v0   = (const float2*)d_in[7];
    float* out = (float*)d_out;
    const int nE = in_sizes[0];

    float*    pp   = (float*)d_ws;                       // [0, 2048) pair partials
    float*    evp  = pp + PAIR_BLOCKS;                   // [2048, 2304) event partials
    unsigned* cnt  = (unsigned*)((char*)d_ws + CNT_OFF); // completion counter

    hipMemsetAsync((void*)cnt, 0, sizeof(unsigned), stream);
    ev_kernel<<<EV_BLOCKS, BLK, 0, stream>>>(eu, ev, et, z0, v0, evp, nE);
    pair_kernel<<<PAIR_BLOCKS, BLK, 0, stream>>>(z0, v0, beta, t0, tn,
                                                 pp, evp, cnt, out, nE);
}

// Round 4
// 39.522 us; speedup vs baseline: 1.7410x; 1.7410x over previous
//
#include <hip/hip_runtime.h>
#include <math.h>

#define NPTS 4096
#define BLK 256
#define COPIES 64
#define PAIR_BLOCKS (16 * COPIES)      // 1024 blocks: g = bid & 15 (j-group), c = bid >> 4
#define RPT 32                         // rows per thread (2048 / COPIES)
#define EVB 256                        // event blocks
#define EVT 1024                       // event threads per block
#define CNT_OFF ((PAIR_BLOCKS + EVB) * 4)

// ---------------- fast erf: Abramowitz-Stegun 7.1.26, |err| <= 1.5e-7 ----------------
__device__ __forceinline__ float fast_erf(float x) {
    const float ax = fabsf(x);
    const float t  = __builtin_amdgcn_rcpf(fmaf(0.3275911f, ax, 1.0f));
    float p = fmaf(t, 1.061405429f, -1.453152027f);
    p = fmaf(t, p, 1.421413741f);
    p = fmaf(t, p, -0.284496736f);
    p = fmaf(t, p, 0.254829592f);
    p *= t;
    const float e = __expf(-ax * ax);
    const float r = fmaf(-p, e, 1.0f);
    return copysignf(r, x);
}

__device__ __forceinline__ float wave_reduce(float v) {
    #pragma unroll
    for (int off = 32; off > 0; off >>= 1)
        v += __shfl_down(v, off, 64);
    return v;   // valid in lane 0
}

// ---------------- kernel 1: event intensity, float4 LDS table ----------------
__global__ __launch_bounds__(EVT) void ev_kernel(
        const int* __restrict__ eu, const int* __restrict__ ev,
        const float* __restrict__ et,
        const float2* __restrict__ z0, const float2* __restrict__ v0,
        float* __restrict__ evp, unsigned* __restrict__ cnt, int nE) {
    __shared__ float4 tab[NPTS];   // exactly 64 KB; reused for the block reduction
    for (int k = threadIdx.x; k < NPTS; k += EVT) {
        const float2 z = z0[k];
        const float2 v = v0[k];
        tab[k] = make_float4(z.x, z.y, v.x, v.y);
    }
    if (blockIdx.x == 0 && threadIdx.x == 0) *cnt = 0;  // reset pair completion counter
    __syncthreads();

    const int base = blockIdx.x * EVT + threadIdx.x;
    int   u[4], w[4];
    float t[4];
    bool  act[4];
    #pragma unroll
    for (int k = 0; k < 4; ++k) {
        const int idx = base + k * (EVB * EVT);
        act[k] = (idx < nE);
        const int safe = act[k] ? idx : 0;
        u[k] = eu[safe]; w[k] = ev[safe]; t[k] = et[safe];
    }
    float acc = 0.f;
    #pragma unroll
    for (int k = 0; k < 4; ++k) {
        const float4 A = tab[u[k]];
        const float4 B = tab[w[k]];
        const float dx = fmaf(A.z - B.z, t[k], A.x - B.x);
        const float dy = fmaf(A.w - B.w, t[k], A.y - B.y);
        const float d2 = fmaf(dx, dx, dy * dy);
        acc += act[k] ? d2 : 0.f;
    }

    const float r = wave_reduce(acc);
    __syncthreads();                       // staging reads done; reuse tab as scratch
    float* red = (float*)tab;
    const int lane = threadIdx.x & 63;
    const int wid  = threadIdx.x >> 6;     // [0, 16)
    if (lane == 0) red[wid] = r;
    __syncthreads();
    if (threadIdx.x == 0) {
        float s = 0.f;
        #pragma unroll
        for (int k = 0; k < EVT / 64; ++k) s += red[k];
        evp[blockIdx.x] = s;
    }
}

// ---------------- pair body: MODE 0 = all-direct, 1 = all-fold, 2 = mixed ----------------
template<int MODE>
__device__ __forceinline__ float pair_rows(const float2* __restrict__ z0,
                                           const float2* __restrict__ v0,
                                           int c, int j,
                                           float t0, float tn, float C) {
    const int jf = NPTS - 1 - j;
    float zjx_d = 0.f, zjy_d = 0.f, vjx_d = 0.f, vjy_d = 0.f;
    float zjx_f = 0.f, zjy_f = 0.f, vjx_f = 0.f, vjy_f = 0.f;
    if (MODE != 1) { const float2 z = z0[j];  const float2 v = v0[j];
                     zjx_d = z.x; zjy_d = z.y; vjx_d = v.x; vjy_d = v.y; }
    if (MODE != 0) { const float2 z = z0[jf]; const float2 v = v0[jf];
                     zjx_f = z.x; zjy_f = z.y; vjx_f = v.x; vjy_f = v.y; }

    float acc = 0.f;
    #pragma unroll 4
    for (int k = 0; k < RPT; ++k) {
        const int r = c * RPT + k;            // wave-uniform -> scalar loads
        float a, bb, m, n;
        bool valid = true;
        if (MODE == 0) {
            const float2 zr = z0[r], vr = v0[r];
            a = zr.x - zjx_d; bb = zr.y - zjy_d; m = vr.x - vjx_d; n = vr.y - vjy_d;
        } else if (MODE == 1) {
            const int rf = NPTS - 1 - r;
            const float2 zr = z0[rf], vr = v0[rf];
            a = zr.x - zjx_f; bb = zr.y - zjy_f; m = vr.x - vjx_f; n = vr.y - vjy_f;
        } else {
            const int rf = NPTS - 1 - r;
            const float2 zr  = z0[r],  vr  = v0[r];
            const float2 zrf = z0[rf], vrf = v0[rf];
            const bool fold = (j < r);
            a  = fold ? (zrf.x - zjx_f) : (zr.x - zjx_d);
            bb = fold ? (zrf.y - zjy_f) : (zr.y - zjy_d);
            m  = fold ? (vrf.x - vjx_f) : (vr.x - vjx_d);
            n  = fold ? (vrf.y - vjy_f) : (vr.y - vjy_d);
            valid = (j != r);
        }

        const float s2    = fmaf(m, m, n * n);
        const float inv_s = __builtin_amdgcn_rsqf(s2);
        const float cross = fmaf(bb, m, -a * n);
        const float am    = fmaf(a, m, bb * n);
        const float q     = cross * inv_s;
        const float E     = __expf(-q * q);
        const float e1    = fast_erf(fmaf(s2, t0, am) * inv_s);
        const float e2    = fast_erf(fmaf(s2, tn, am) * inv_s);

        float contrib = (C * E) * (e1 - e2) * inv_s;
        if (MODE == 2) contrib = valid ? contrib : 0.f;
        acc += contrib;
    }
    return acc;
}

// ---------------- kernel 2: pair integral; last block does deterministic combine ----------------
__global__ __launch_bounds__(BLK, 4) void pair_kernel(
        const float2* __restrict__ z0, const float2* __restrict__ v0,
        const float* __restrict__ beta_p, const float* __restrict__ t0_p,
        const float* __restrict__ tn_p,
        float* __restrict__ pp, const float* __restrict__ evp,
        unsigned* __restrict__ cnt, float* __restrict__ out, int nE) {
    const int g = blockIdx.x & 15;        // j-group
    const int c = blockIdx.x >> 4;        // row-chunk: r in [c*RPT, c*RPT+RPT)
    const int j = g * BLK + threadIdx.x;

    const float b  = beta_p[0];
    const float t0 = t0_p[0];
    const float tn = tn_p[0];
    const float C  = -0.88622692545275801365f * __expf(b);   // -sqrt(pi)/2 * e^b

    float acc;
    if (c < 8 * g)                acc = pair_rows<0>(z0, v0, c, j, t0, tn, C);
    else if (c >= 8 * (g + 1))    acc = pair_rows<1>(z0, v0, c, j, t0, tn, C);
    else                          acc = pair_rows<2>(z0, v0, c, j, t0, tn, C);

    // block reduce
    float r = wave_reduce(acc);
    __shared__ float smem[BLK / 64];
    const int lane = threadIdx.x & 63;
    const int wid  = threadIdx.x >> 6;
    if (lane == 0) smem[wid] = r;
    __syncthreads();

    __shared__ bool amLast;
    if (threadIdx.x == 0) {
        float s = 0.f;
        #pragma unroll
        for (int k = 0; k < BLK / 64; ++k) s += smem[k];
        __hip_atomic_store(&pp[blockIdx.x], s, __ATOMIC_RELEASE, __HIP_MEMORY_SCOPE_AGENT);
        const unsigned old = __hip_atomic_fetch_add(cnt, 1u, __ATOMIC_ACQ_REL,
                                                    __HIP_MEMORY_SCOPE_AGENT);
        amLast = (old == PAIR_BLOCKS - 1);
    }
    __syncthreads();

    if (amLast) {
        __shared__ double sd[BLK];
        double s = 0.0;
        #pragma unroll
        for (int k = threadIdx.x; k < PAIR_BLOCKS; k += BLK)
            s += (double)__hip_atomic_load(&pp[k], __ATOMIC_RELAXED,
                                           __HIP_MEMORY_SCOPE_AGENT);
        s += (double)evp[threadIdx.x];   // EVB == BLK
        sd[threadIdx.x] = s;
        __syncthreads();
        for (int st = BLK / 2; st > 0; st >>= 1) {
            if (threadIdx.x < st) sd[threadIdx.x] += sd[threadIdx.x + st];
            __syncthreads();
        }
        if (threadIdx.x == 0)
            out[0] = (float)((double)nE * (double)b - sd[0]);
    }
}

extern "C" void kernel_launch(void* const* d_in, const int* in_sizes, int n_in,
                              void* d_out, int out_size, void* d_ws, size_t ws_size,
                              hipStream_t stream) {
    const int*    eu   = (const int*)d_in[0];
    const int*    ev   = (const int*)d_in[1];
    const float*  et   = (const float*)d_in[2];
    const float*  t0   = (const float*)d_in[3];
    const float*  tn   = (const float*)d_in[4];
    const float*  beta = (const float*)d_in[5];
    const float2* z0   = (const float2*)d_in[6];
    const float2* v0   = (const float2*)d_in[7];
    float* out = (float*)d_out;
    const int nE = in_sizes[0];

    float*    pp  = (float*)d_ws;                        // [0, 1024) pair partials
    float*    evp = pp + PAIR_BLOCKS;                    // [1024, 1280) event partials
    unsigned* cnt = (unsigned*)((char*)d_ws + CNT_OFF);  // completion counter

    ev_kernel<<<EVB, EVT, 0, stream>>>(eu, ev, et, z0, v0, evp, cnt, nE);
    pair_kernel<<<PAIR_BLOCKS, BLK, 0, stream>>>(z0, v0, beta, t0, tn,
                                                 pp, evp, cnt, out, nE);
}